// Round 16
// baseline (139.817 us; speedup 1.0000x reference)
//
#include <hip/hip_runtime.h>
#include <math.h>

#define LATN 721
#define LONN 1440
#define NLEV 13
#define NBATCH 2
#define SLICE (LATN * LONN)              // 1,038,240
#define BATSTRIDE (NLEV * SLICE)

// geometry: thread = 2 output rows x 2 cols (float2); wave = 128 cols, 124 outputs
#define OUTW 124                         // outputs per wave (lanes 1..62, 2 cols each)
#define WGCOLS 496                       // 4 waves
#define SEGS 3                           // ceil(1440/496)
#define NROWP 361                        // ceil(721/2) row-pairs
#define NWGX (NROWP * SEGS)              // 1083

// ---- ws float layout ----
#define NBANK      128
#define BANKSTRIDE 64
#define WS_ACC     0                     // [NBANK*BANKSTRIDE]
#define ACC_SUM    0        // [26] per (b,l) sums
#define ACC_SSQ    26       // [2]  per-batch total sum-of-squares
#define ACC_GRAD   28
#define ACC_MASS   29
#define N_ACC      30
#define WS_INVDX   (NBANK * BANKSTRIDE)          // [721]
#define WS_FCOR    (WS_INVDX + LATN)             // [721]
#define WS_W       (WS_FCOR + LATN)              // [13]
#define WS_INVDP   (WS_W + NLEV)
#define WS_INV2DP  (WS_INVDP + 1)

constexpr float INV_R     = (float)(1.0 / 6371000.0);
constexpr float INV_DLAT  = (float)(720.0 / M_PI);
constexpr float INV_2DLAT = (float)(360.0 / M_PI);
constexpr float INV_DLON  = (float)(1440.0 / (2.0 * M_PI));
constexpr float INV_2DLON = (float)(720.0 / (2.0 * M_PI));
constexpr float QG_COEF   = 1e-4f;   // F0^2 / N^2

// ---------------- setup: row tables, weights, zero accumulators ----------------
__global__ void pl_setup_kernel(const float* __restrict__ plev, float* __restrict__ ws) {
    const int t = threadIdx.x;
    if (t < LATN) {
        double lat;
        if (t == 0)            lat = (double)(-(float)(M_PI / 2.0));
        else if (t == LATN-1)  lat = (double)( (float)(M_PI / 2.0));
        else                   lat = (double)((float)(-M_PI / 2.0 + (double)t * (M_PI / 720.0)));
        double c = cos(lat);
        if (c < 1e-8) c = 1e-8;                      // matches jnp.clip(cos, 1e-8)
        ws[WS_INVDX + t] = (float)(1.0 / (6371000.0 * c));
        ws[WS_FCOR  + t] = (float)(2.0 * 7.292e-05 * sin(lat));
    }
    if (t < NLEV) {
        float p[NLEV];
        #pragma unroll
        for (int l = 0; l < NLEV; ++l) p[l] = plev[l] * 100.0f;
        float dpl[NLEV-1];
        #pragma unroll
        for (int l = 0; l < NLEV-1; ++l) dpl[l] = p[l+1] - p[l];
        float raw;
        if (t == 0)            raw = dpl[0] * 0.5f;
        else if (t == NLEV-1)  raw = dpl[NLEV-2] * 0.5f;
        else                   raw = (dpl[t-1] + dpl[t]) * 0.5f;
        float s = dpl[0] * 0.5f + dpl[NLEV-2] * 0.5f;
        #pragma unroll
        for (int l = 1; l < NLEV-1; ++l) s += (dpl[l-1] + dpl[l]) * 0.5f;
        if (s < 1e-8f) s = 1e-8f;
        ws[WS_W + t] = raw / s;
    }
    if (t == 0) {
        float sd = 0.f;
        for (int l = 0; l < NLEV-1; ++l) sd += plev[l+1] - plev[l];
        float dp = sd / (float)(NLEV-1) * 100.0f;    // mean(diff)*100 (hPa->Pa)
        ws[WS_INVDP]  = 1.0f / dp;
        ws[WS_INV2DP] = 1.0f / (2.0f * dp);
    }
    for (int z = t; z < NBANK * BANKSTRIDE; z += 1024) ws[WS_ACC + z] = 0.0f;
}

// ---------------- helpers ----------------
__device__ __forceinline__ int swz_nwg(int orig, int nwg) {
    // bijective XCD-chunk swizzle (m204)
    const int q = nwg >> 3, r = nwg & 7;
    const int x = orig & 7, k = orig >> 3;
    return (x < r ? x * (q + 1) : r * (q + 1) + (x - r) * q) + k;
}
__device__ __forceinline__ float2 ld2(const float* p) {
    return *reinterpret_cast<const float2*>(p);
}
typedef float f4u __attribute__((ext_vector_type(4)));
struct __attribute__((packed, aligned(4))) f4u_box { f4u v; };
__device__ __forceinline__ f4u ld4u(const float* p) {   // element-aligned 16B load
    return reinterpret_cast<const f4u_box*>(p)->v;
}
__device__ __forceinline__ float2 sm2(float2 a, float2 b, float s) {   // (a-b)*s
    return make_float2((a.x - b.x) * s, (a.y - b.y) * s);
}

// ---------------- fused kernel: R13 + shfl-free vort (v as unaligned float4) ----------------
// R15 isolated: depth-2 prefetch neutral -> latency covered at depth-1. Residual is the
// per-level ds_bpermute chain (8 shfls) on the vort critical path; this removes it by
// loading v[cb-1..cb+2] in-lane (bitwise-identical operands, case-analyzed edges).
__launch_bounds__(256)
__global__ void pl_rc22s_kernel(const float* __restrict__ u, const float* __restrict__ v,
                                float* __restrict__ ws)
{
    __shared__ float red[16][17];

    const int tid  = threadIdx.x;
    const int lane = tid & 63, w = tid >> 6;
    const int b  = blockIdx.y;
    const int wg = swz_nwg(blockIdx.x, NWGX);
    const int wgr = wg / SEGS, seg = wg - wgr * SEGS;
    const int r0  = 2 * wgr;                         // 0,2,...,720

    // columns: lane owns pair (c0, c0+1); lanes 1..62 are outputs, 0/63 shfl halo
    const int out0  = seg * WGCOLS + w * OUTW;
    const int c0_un = out0 - 2 + 2 * lane;           // even
    const int cb = max(0, min(c0_un, LONN - 2));     // 8B-aligned pair base
    const int vcb = max(0, min(cb - 1, LONN - 4));   // v float4 base (4B-aligned)
    const float m0 = (lane >= 1 && lane <= 62 && c0_un     < LONN) ? 1.f : 0.f;
    const float m1 = (lane >= 1 && lane <= 62 && c0_un + 1 < LONN) ? 1.f : 0.f;
    const bool e0 = (c0_un == 0);                    // .x is col 0 (parity: always .x)
    const bool e1 = (c0_un + 1 == LONN - 1);         // .y is col 1439 (always .y)

    // rows: outputs r0 (a), r0+1 (b); vort rows m=r0-1, a, b, p=r0+2
    const bool rTop = (r0 == 0), rBotA = (r0 == LATN - 1);
    const float rbf = (r0 + 1 < LATN) ? 1.f : 0.f;
    const float mb0 = m0 * rbf, mb1 = m1 * rbf;
    const int crm = max(r0 - 1, 0);
    const int crb = min(r0 + 1, LATN - 1);
    const int crp = min(r0 + 2, LATN - 1);
    const int cu0 = max(r0 - 2, 0), cu1 = crm, cu2 = r0;
    const int cu3 = crb, cu4 = crp, cu5 = min(r0 + 3, LATN - 1);

    const float idp = ws[WS_INVDP], i2dp = ws[WS_INV2DP];

    // scales: eC0/eC1 fold per-column one-sided factor
    const float eC0 = e0 ? INV_DLON : INV_2DLON;
    const float eC1 = e1 ? INV_DLON : INV_2DLON;
    const float ixm = ws[WS_INVDX + crm], ixa = ws[WS_INVDX + r0];
    const float ixb = ws[WS_INVDX + crb], ixp = ws[WS_INVDX + crp];
    const float sm0 = eC0 * ixm, sm1 = eC1 * ixm;
    const float sa0 = eC0 * ixa, sa1 = eC1 * ixa;
    const float sb0 = eC0 * ixb, sb1 = eC1 * ixb;
    const float sp0 = eC0 * ixp, sp1 = eC1 * ixp;
    const float sr_a = ((rTop || rBotA) ? INV_DLAT : INV_2DLAT) * INV_R;
    const float sr_mb = INV_2DLAT * INV_R;           // rows m/b never grid-edge (parity)
    const float sr_p = ((r0 + 2 >= LATN - 1) ? INV_DLAT : INV_2DLAT) * INV_R;
    const float fc_m = ws[WS_FCOR + crm], fc_a = ws[WS_FCOR + r0];
    const float fc_b = ws[WS_FCOR + crb], fc_p = ws[WS_FCOR + crp];

    // element offsets; level advance = uniform SGPR pointer bump
    const int o_u0 = cu0 * LONN + cb, o_u1 = cu1 * LONN + cb, o_u2 = cu2 * LONN + cb;
    const int o_u3 = cu3 * LONN + cb, o_u4 = cu4 * LONN + cb, o_u5 = cu5 * LONN + cb;
    const int o_vm = crm * LONN + vcb, o_va = r0 * LONN + vcb;
    const int o_vb = crb * LONN + vcb, o_vp = crp * LONN + vcb;

    // level weights preloaded (static index after unroll)
    float wlev[NLEV];
    #pragma unroll
    for (int l = 0; l < NLEV; ++l) wlev[l] = ws[WS_W + l];

    float vals[16];
    #pragma unroll
    for (int k = 0; k < 16; ++k) vals[k] = 0.f;
    float ssqt = 0.f, grad = 0.f;
    float2 wu_a = make_float2(0.f, 0.f), wu_b = make_float2(0.f, 0.f);
    float2 wvm = make_float2(0.f, 0.f), wva = make_float2(0.f, 0.f);
    float2 wvb = make_float2(0.f, 0.f), wvp = make_float2(0.f, 0.f);

    auto qgf = [&](float2 vo, float fc, float2 vpp) -> float2 {
        return make_float2(vo.x + fc + QG_COEF * vpp.x, vo.y + fc + QG_COEF * vpp.y);
    };
    auto consume = [&](int k, float2 qm, float2 qa, float2 qb, float2 qp) {
        const float qax = qa.x * m0,  qay = qa.y * m1;
        const float qbx = qb.x * mb0, qby = qb.y * mb1;
        vals[k] += (qax + qay) + (qbx + qby);
        ssqt += qax * qax + qay * qay + qbx * qbx + qby * qby;
        const float2 gla = sm2(qb, qm, sr_a);        // row clamps folded via vo selects
        const float2 glb = sm2(qp, qa, sr_mb);
        const float qaL = __shfl_up(qa.y, 1), qaR = __shfl_down(qa.x, 1);
        const float qbL = __shfl_up(qb.y, 1), qbR = __shfl_down(qb.x, 1);
        const float gnax = (qa.y - (e0 ? qa.x : qaL)) * sa0;
        const float gnay = ((e1 ? qa.y : qaR) - qa.x) * sa1;
        const float gnbx = (qb.y - (e0 ? qb.x : qbL)) * sb0;
        const float gnby = ((e1 ? qb.y : qbR) - qb.x) * sb1;
        grad += m0  * (gla.x * gla.x + gnax * gnax) + m1  * (gla.y * gla.y + gnay * gnay)
              + mb0 * (glb.x * glb.x + gnbx * gnbx) + mb1 * (glb.y * glb.y + gnby * gnby);
    };

    // rolling state ONLY (R8/R11 lesson: NO level-indexed arrays)
    float2 vo2_m, vo1_m, pa_m, pb_m;
    float2 vo2_a, vo1_a, pa_a, pb_a;
    float2 vo2_b, vo1_b, pa_b, pb_b;
    float2 vo2_p, vo1_p, pa_p, pb_p;

    // named double-buffer registers (a / b) — statically swapped via even/odd unroll
    float2 u0a, u1a, u2a, u3a, u4a, u5a;
    float2 u0b, u1b, u2b, u3b, u4b, u5b;
    f4u vma, vaa, vba, vpa;
    f4u vmb, vab, vbb, vpb;

    const float* pu = u + (size_t)b * BATSTRIDE;
    const float* pv = v + (size_t)b * BATSTRIDE;

    #define LOADSET(S) do {                                                     \
        u0##S = ld2(pu + o_u0); u1##S = ld2(pu + o_u1); u2##S = ld2(pu + o_u2); \
        u3##S = ld2(pu + o_u3); u4##S = ld2(pu + o_u4); u5##S = ld2(pu + o_u5); \
        vm##S = ld4u(pv + o_vm); va##S = ld4u(pv + o_va);                       \
        vb##S = ld4u(pv + o_vb); vp##S = ld4u(pv + o_vp);                       \
        pu += SLICE; pv += SLICE;                                               \
    } while (0)

    // in-lane v col-diffs and self values (case-analyzed: interior/e0/e1)
    //   interior: d0=.z-.x  d1=.w-.y  s0=.y  s1=.z
    //   e0:       d0=.y-.x  d1=.z-.x  s0=.x  s1=.y
    //   e1:       d0=.w-.y  d1=.w-.z  s0=.z  s1=.w
    #define VDIF0(V) (e0 ? ((V).y - (V).x) : (e1 ? ((V).w - (V).y) : ((V).z - (V).x)))
    #define VDIF1(V) (e0 ? ((V).z - (V).x) : (e1 ? ((V).w - (V).z) : ((V).w - (V).y)))
    #define VSELF0(V) (e0 ? (V).x : (e1 ? (V).z : (V).y))
    #define VSELF1(V) (e0 ? (V).y : (e1 ? (V).w : (V).z))

    // COMPUTE(L, S): R13's level body with shfl-free vort (identical operand values)
    #define COMPUTE(L, S) do {                                                            \
        const float wl = wlev[(L)];                                                       \
        wu_a.x = fmaf(wl, u2##S.x, wu_a.x);  wu_a.y = fmaf(wl, u2##S.y, wu_a.y);          \
        wu_b.x = fmaf(wl, u3##S.x, wu_b.x);  wu_b.y = fmaf(wl, u3##S.y, wu_b.y);          \
        wvm.x = fmaf(wl, VSELF0(vm##S), wvm.x);  wvm.y = fmaf(wl, VSELF1(vm##S), wvm.y);  \
        wva.x = fmaf(wl, VSELF0(va##S), wva.x);  wva.y = fmaf(wl, VSELF1(va##S), wva.y);  \
        wvb.x = fmaf(wl, VSELF0(vb##S), wvb.x);  wvb.y = fmaf(wl, VSELF1(vb##S), wvb.y);  \
        wvp.x = fmaf(wl, VSELF0(vp##S), wvp.x);  wvp.y = fmaf(wl, VSELF1(vp##S), wvp.y);  \
        float2 com, coa, cob, cop;                                                        \
        com.x = VDIF0(vm##S) * sm0 - (u2##S.x - u0##S.x) * sr_mb;                         \
        com.y = VDIF1(vm##S) * sm1 - (u2##S.y - u0##S.y) * sr_mb;                         \
        coa.x = VDIF0(va##S) * sa0 - (u3##S.x - u1##S.x) * sr_a;                          \
        coa.y = VDIF1(va##S) * sa1 - (u3##S.y - u1##S.y) * sr_a;                          \
        cob.x = VDIF0(vb##S) * sb0 - (u4##S.x - u2##S.x) * sr_mb;                         \
        cob.y = VDIF1(vb##S) * sb1 - (u4##S.y - u2##S.y) * sr_mb;                         \
        cop.x = VDIF0(vp##S) * sp0 - (u5##S.x - u3##S.x) * sr_p;                          \
        cop.y = VDIF1(vp##S) * sp1 - (u5##S.y - u3##S.y) * sr_p;                          \
        if (rTop)  com = coa;                        /* clamped halo row == own row */    \
        if (rBotA) { cob = coa; cop = coa; }                                              \
        if ((L) == 0) {                                                                   \
            vo1_m = com; vo1_a = coa; vo1_b = cob; vo1_p = cop;                           \
        } else if ((L) == 1) {                                                            \
            pb_m = sm2(com, vo1_m, idp);  pb_a = sm2(coa, vo1_a, idp);                    \
            pb_b = sm2(cob, vo1_b, idp);  pb_p = sm2(cop, vo1_p, idp);                    \
            vo2_m = vo1_m; vo1_m = com;   vo2_a = vo1_a; vo1_a = coa;                     \
            vo2_b = vo1_b; vo1_b = cob;   vo2_p = vo1_p; vo1_p = cop;                     \
        } else {                                                                          \
            const float2 pn_m = sm2(com, vo2_m, i2dp);   /* vp1[l-1] */                   \
            const float2 pn_a = sm2(coa, vo2_a, i2dp);                                    \
            const float2 pn_b = sm2(cob, vo2_b, i2dp);                                    \
            const float2 pn_p = sm2(cop, vo2_p, i2dp);                                    \
            float2 qm, qa, qb, qp;                                                        \
            if ((L) == 2) {                                                               \
                qm = qgf(vo2_m, fc_m, sm2(pn_m, pb_m, idp));                              \
                qa = qgf(vo2_a, fc_a, sm2(pn_a, pb_a, idp));                              \
                qb = qgf(vo2_b, fc_b, sm2(pn_b, pb_b, idp));                              \
                qp = qgf(vo2_p, fc_p, sm2(pn_p, pb_p, idp));                              \
            } else {                                                                      \
                qm = qgf(vo2_m, fc_m, sm2(pn_m, pa_m, i2dp));                             \
                qa = qgf(vo2_a, fc_a, sm2(pn_a, pa_a, i2dp));                             \
                qb = qgf(vo2_b, fc_b, sm2(pn_b, pa_b, i2dp));                             \
                qp = qgf(vo2_p, fc_p, sm2(pn_p, pa_p, i2dp));                             \
            }                                                                             \
            consume((L) - 2, qm, qa, qb, qp);                                             \
            pa_m = pb_m; pb_m = pn_m;  vo2_m = vo1_m; vo1_m = com;                        \
            pa_a = pb_a; pb_a = pn_a;  vo2_a = vo1_a; vo1_a = coa;                        \
            pa_b = pb_b; pb_b = pn_b;  vo2_b = vo1_b; vo1_b = cob;                        \
            pa_p = pb_p; pb_p = pn_p;  vo2_p = vo1_p; vo1_p = cop;                        \
        }                                                                                 \
    } while (0)

    // ---- level loop: prefetch(l+1) issued BEFORE compute(l); depth-1 (R15: depth-2 neutral) ----
    LOADSET(a);                                   // level 0
    #pragma unroll
    for (int l = 0; l < NLEV; ++l) {
        if ((l & 1) == 0) {
            if (l + 1 < NLEV) LOADSET(b);
            COMPUTE(l, a);
        } else {
            if (l + 1 < NLEV) LOADSET(a);
            COMPUTE(l, b);
        }
        __builtin_amdgcn_sched_barrier(0);        // bound hoisting to 1 level (R11 lesson)
    }
    #undef LOADSET
    #undef COMPUTE
    #undef VDIF0
    #undef VDIF1
    #undef VSELF0
    #undef VSELF1

    // tail: vp1[12] one-sided; emit qg[11], qg[12]
    {
        const float2 p12m = sm2(vo1_m, vo2_m, idp);
        const float2 p12a = sm2(vo1_a, vo2_a, idp);
        const float2 p12b = sm2(vo1_b, vo2_b, idp);
        const float2 p12p = sm2(vo1_p, vo2_p, idp);
        consume(11, qgf(vo2_m, fc_m, sm2(p12m, pa_m, i2dp)),
                    qgf(vo2_a, fc_a, sm2(p12a, pa_a, i2dp)),
                    qgf(vo2_b, fc_b, sm2(p12b, pa_b, i2dp)),
                    qgf(vo2_p, fc_p, sm2(p12p, pa_p, i2dp)));
        consume(12, qgf(vo1_m, fc_m, sm2(p12m, pb_m, idp)),
                    qgf(vo1_a, fc_a, sm2(p12a, pb_a, idp)),
                    qgf(vo1_b, fc_b, sm2(p12b, pb_b, idp)),
                    qgf(vo1_p, fc_p, sm2(p12p, pb_p, idp)));
    }

    vals[13] += ssqt;
    vals[14] += grad;
    // mass: du/dx in-lane/shfl + edge selects; dv/dy in-thread (clamped loads -> exact edges)
    {
        const float waL = __shfl_up(wu_a.y, 1), waR = __shfl_down(wu_a.x, 1);
        const float wbL = __shfl_up(wu_b.y, 1), wbR = __shfl_down(wu_b.x, 1);
        const float cdax = (wu_a.y - (e0 ? wu_a.x : waL)) * sa0 + (wvb.x - wvm.x) * sr_a;
        const float cday = ((e1 ? wu_a.y : waR) - wu_a.x) * sa1 + (wvb.y - wvm.y) * sr_a;
        const float cdbx = (wu_b.y - (e0 ? wu_b.x : wbL)) * sb0 + (wvp.x - wva.x) * sr_mb;
        const float cdby = ((e1 ? wu_b.y : wbR) - wu_b.x) * sb1 + (wvp.y - wva.y) * sr_mb;
        vals[15] += m0 * cdax * cdax + m1 * cday * cday
                  + mb0 * cdbx * cdbx + mb1 * cdby * cdby;
    }

    // ---- reduction: 4-step 16-lane-group butterfly + LDS transpose (16 values) ----
    #pragma unroll
    for (int k = 0; k < 16; ++k) {
        float x = vals[k];
        x += __shfl_xor(x, 8, 64);
        x += __shfl_xor(x, 4, 64);
        x += __shfl_xor(x, 2, 64);
        x += __shfl_xor(x, 1, 64);
        vals[k] = x;
    }
    const int g = tid >> 4, k16 = tid & 15;
    float myv = vals[0];
    #pragma unroll
    for (int k = 1; k < 16; ++k) if (k16 == k) myv = vals[k];   // static-index select
    red[g][k16] = myv;
    __syncthreads();

    if (tid < 16) {
        const int k = tid;
        float s = 0.f;
        #pragma unroll
        for (int g2 = 0; g2 < 16; ++g2) s += red[g2][k];
        int target;
        if (k < 13)       target = ACC_SUM + b * 13 + k;
        else if (k == 13) target = ACC_SSQ + b;
        else if (k == 14) target = ACC_GRAD;
        else              target = ACC_MASS;
        const int bank = (b * NWGX + blockIdx.x) & (NBANK - 1);
        atomicAdd(&ws[WS_ACC + bank * BANKSTRIDE + target], s);
    }
}

// ---------------- finalize: sum banks, apply formulas ----------------
__global__ void pl_finalize_kernel(const float* __restrict__ ws, float* __restrict__ out) {
    __shared__ float tot[N_ACC];
    const int t = threadIdx.x;
    if (t < N_ACC) {
        float s = 0.f;
        for (int bk = 0; bk < NBANK; ++bk) s += ws[WS_ACC + bk * BANKSTRIDE + t];
        tot[t] = s;
    }
    __syncthreads();
    if (t == 0) {
        const float N = (float)SLICE;
        float s2 = 0.f;
        for (int s = 0; s < 2 * NLEV; ++s) s2 += tot[ACC_SUM + s] * tot[ACC_SUM + s];
        const float ssq = tot[ACC_SSQ + 0] + tot[ACC_SSQ + 1];
        float vmean = (ssq - s2 / N) / (N - 1.0f) * (1.0f / (2.0f * NLEV));
        float gmean = tot[ACC_GRAD] / (float)(NBATCH * NLEV * SLICE);
        float mmean = tot[ACC_MASS] / (float)(NBATCH * SLICE);
        out[0] = vmean + 0.1f * gmean + mmean;          // spectra_loss statically 0
    }
}

extern "C" void kernel_launch(void* const* d_in, const int* in_sizes, int n_in,
                              void* d_out, int out_size, void* d_ws, size_t ws_size,
                              hipStream_t stream) {
    const float* u    = (const float*)d_in[0];
    const float* v    = (const float*)d_in[1];
    const float* plev = (const float*)d_in[2];
    float* ws  = (float*)d_ws;
    float* out = (float*)d_out;

    hipLaunchKernelGGL(pl_setup_kernel, dim3(1), dim3(1024), 0, stream, plev, ws);
    hipLaunchKernelGGL(pl_rc22s_kernel, dim3(NWGX, NBATCH), dim3(256), 0, stream, u, v, ws);
    hipLaunchKernelGGL(pl_finalize_kernel, dim3(1), dim3(64), 0, stream, ws, out);
}

// Round 17
// 54.575 us; speedup vs baseline: 2.5619x; 2.5619x over previous
//
#include <hip/hip_runtime.h>
#include <math.h>

#define LATN 721
#define LONN 1440
#define NLEV 13
#define NBATCH 2
#define SLICE (LATN * LONN)              // 1,038,240
#define BATSTRIDE (NLEV * SLICE)

// geometry: thread = 2 output rows x 2 cols (float2); wave = 128 cols, 124 outputs
#define OUTW 124                         // outputs per wave (lanes 1..62, 2 cols each)
#define WGCOLS 496                       // 4 waves
#define SEGS 3                           // ceil(1440/496)
#define NROWP 361                        // ceil(721/2) row-pairs
#define NWGX (NROWP * SEGS)              // 1083

// ---- ws float layout ----
#define NBANK      128
#define BANKSTRIDE 64
#define WS_ACC     0                     // [NBANK*BANKSTRIDE]
#define ACC_SUM    0        // [26] per (b,l) sums
#define ACC_SSQ    26       // [2]  per-batch total sum-of-squares
#define ACC_GRAD   28
#define ACC_MASS   29
#define N_ACC      30
#define WS_INVDX   (NBANK * BANKSTRIDE)          // [721]
#define WS_FCOR    (WS_INVDX + LATN)             // [721]
#define WS_W       (WS_FCOR + LATN)              // [13]
#define WS_INVDP   (WS_W + NLEV)
#define WS_INV2DP  (WS_INVDP + 1)

constexpr float INV_R     = (float)(1.0 / 6371000.0);
constexpr float INV_DLAT  = (float)(720.0 / M_PI);
constexpr float INV_2DLAT = (float)(360.0 / M_PI);
constexpr float INV_DLON  = (float)(1440.0 / (2.0 * M_PI));
constexpr float INV_2DLON = (float)(720.0 / (2.0 * M_PI));
constexpr float QG_COEF   = 1e-4f;   // F0^2 / N^2

// ---------------- setup: row tables, weights, zero accumulators ----------------
__global__ void pl_setup_kernel(const float* __restrict__ plev, float* __restrict__ ws) {
    const int t = threadIdx.x;
    if (t < LATN) {
        double lat;
        if (t == 0)            lat = (double)(-(float)(M_PI / 2.0));
        else if (t == LATN-1)  lat = (double)( (float)(M_PI / 2.0));
        else                   lat = (double)((float)(-M_PI / 2.0 + (double)t * (M_PI / 720.0)));
        double c = cos(lat);
        if (c < 1e-8) c = 1e-8;                      // matches jnp.clip(cos, 1e-8)
        ws[WS_INVDX + t] = (float)(1.0 / (6371000.0 * c));
        ws[WS_FCOR  + t] = (float)(2.0 * 7.292e-05 * sin(lat));
    }
    if (t < NLEV) {
        float p[NLEV];
        #pragma unroll
        for (int l = 0; l < NLEV; ++l) p[l] = plev[l] * 100.0f;
        float dpl[NLEV-1];
        #pragma unroll
        for (int l = 0; l < NLEV-1; ++l) dpl[l] = p[l+1] - p[l];
        float raw;
        if (t == 0)            raw = dpl[0] * 0.5f;
        else if (t == NLEV-1)  raw = dpl[NLEV-2] * 0.5f;
        else                   raw = (dpl[t-1] + dpl[t]) * 0.5f;
        float s = dpl[0] * 0.5f + dpl[NLEV-2] * 0.5f;
        #pragma unroll
        for (int l = 1; l < NLEV-1; ++l) s += (dpl[l-1] + dpl[l]) * 0.5f;
        if (s < 1e-8f) s = 1e-8f;
        ws[WS_W + t] = raw / s;
    }
    if (t == 0) {
        float sd = 0.f;
        for (int l = 0; l < NLEV-1; ++l) sd += plev[l+1] - plev[l];
        float dp = sd / (float)(NLEV-1) * 100.0f;    // mean(diff)*100 (hPa->Pa)
        ws[WS_INVDP]  = 1.0f / dp;
        ws[WS_INV2DP] = 1.0f / (2.0f * dp);
    }
    for (int z = t; z < NBANK * BANKSTRIDE; z += 1024) ws[WS_ACC + z] = 0.0f;
}

// ---------------- helpers ----------------
__device__ __forceinline__ int swz_nwg(int orig, int nwg) {
    // bijective XCD-chunk swizzle (m204)
    const int q = nwg >> 3, r = nwg & 7;
    const int x = orig & 7, k = orig >> 3;
    return (x < r ? x * (q + 1) : r * (q + 1) + (x - r) * q) + k;
}
__device__ __forceinline__ float2 ld2(const float* p) {
    return *reinterpret_cast<const float2*>(p);
}
__device__ __forceinline__ float2 sm2(float2 a, float2 b, float s) {   // (a-b)*s
    return make_float2((a.x - b.x) * s, (a.y - b.y) * s);
}

// ---------------- fused kernel: R13 champion restore (2x2/thread + 1-level prefetch) ----------------
// R16 lesson: element-aligned vector loads blow up codegen (VGPR 252) — v loads stay
// aligned float2 + shfl. R15: depth-2 prefetch neutral -> depth-1 is sufficient.
__launch_bounds__(256)
__global__ void pl_rc22p_kernel(const float* __restrict__ u, const float* __restrict__ v,
                                float* __restrict__ ws)
{
    __shared__ float red[16][17];

    const int tid  = threadIdx.x;
    const int lane = tid & 63, w = tid >> 6;
    const int b  = blockIdx.y;
    const int wg = swz_nwg(blockIdx.x, NWGX);
    const int wgr = wg / SEGS, seg = wg - wgr * SEGS;
    const int r0  = 2 * wgr;                         // 0,2,...,720

    // columns: lane owns pair (c0, c0+1); lanes 1..62 are outputs, 0/63 shfl halo
    const int out0  = seg * WGCOLS + w * OUTW;
    const int c0_un = out0 - 2 + 2 * lane;           // even
    const int cb = max(0, min(c0_un, LONN - 2));     // 8B-aligned pair base
    const float m0 = (lane >= 1 && lane <= 62 && c0_un     < LONN) ? 1.f : 0.f;
    const float m1 = (lane >= 1 && lane <= 62 && c0_un + 1 < LONN) ? 1.f : 0.f;
    const bool e0 = (c0_un == 0);                    // .x is col 0 (parity: always .x)
    const bool e1 = (c0_un + 1 == LONN - 1);         // .y is col 1439 (always .y)

    // rows: outputs r0 (a), r0+1 (b); vort rows m=r0-1, a, b, p=r0+2
    const bool rTop = (r0 == 0), rBotA = (r0 == LATN - 1);
    const float rbf = (r0 + 1 < LATN) ? 1.f : 0.f;
    const float mb0 = m0 * rbf, mb1 = m1 * rbf;
    const int crm = max(r0 - 1, 0);
    const int crb = min(r0 + 1, LATN - 1);
    const int crp = min(r0 + 2, LATN - 1);
    const int cu0 = max(r0 - 2, 0), cu1 = crm, cu2 = r0;
    const int cu3 = crb, cu4 = crp, cu5 = min(r0 + 3, LATN - 1);

    const float idp = ws[WS_INVDP], i2dp = ws[WS_INV2DP];

    // scales: eC0/eC1 fold per-column one-sided factor
    const float eC0 = e0 ? INV_DLON : INV_2DLON;
    const float eC1 = e1 ? INV_DLON : INV_2DLON;
    const float ixm = ws[WS_INVDX + crm], ixa = ws[WS_INVDX + r0];
    const float ixb = ws[WS_INVDX + crb], ixp = ws[WS_INVDX + crp];
    const float sm0 = eC0 * ixm, sm1 = eC1 * ixm;
    const float sa0 = eC0 * ixa, sa1 = eC1 * ixa;
    const float sb0 = eC0 * ixb, sb1 = eC1 * ixb;
    const float sp0 = eC0 * ixp, sp1 = eC1 * ixp;
    const float sr_a = ((rTop || rBotA) ? INV_DLAT : INV_2DLAT) * INV_R;
    const float sr_mb = INV_2DLAT * INV_R;           // rows m/b never grid-edge (parity)
    const float sr_p = ((r0 + 2 >= LATN - 1) ? INV_DLAT : INV_2DLAT) * INV_R;
    const float fc_m = ws[WS_FCOR + crm], fc_a = ws[WS_FCOR + r0];
    const float fc_b = ws[WS_FCOR + crb], fc_p = ws[WS_FCOR + crp];

    // element offsets (pair base); level advance = uniform SGPR pointer bump
    const int o_u0 = cu0 * LONN + cb, o_u1 = cu1 * LONN + cb, o_u2 = cu2 * LONN + cb;
    const int o_u3 = cu3 * LONN + cb, o_u4 = cu4 * LONN + cb, o_u5 = cu5 * LONN + cb;
    const int o_vm = crm * LONN + cb, o_va = r0 * LONN + cb;
    const int o_vb = crb * LONN + cb, o_vp = crp * LONN + cb;

    // level weights preloaded (static index after unroll)
    float wlev[NLEV];
    #pragma unroll
    for (int l = 0; l < NLEV; ++l) wlev[l] = ws[WS_W + l];

    float vals[16];
    #pragma unroll
    for (int k = 0; k < 16; ++k) vals[k] = 0.f;
    float ssqt = 0.f, grad = 0.f;
    float2 wu_a = make_float2(0.f, 0.f), wu_b = make_float2(0.f, 0.f);
    float2 wvm = make_float2(0.f, 0.f), wva = make_float2(0.f, 0.f);
    float2 wvb = make_float2(0.f, 0.f), wvp = make_float2(0.f, 0.f);

    auto qgf = [&](float2 vo, float fc, float2 vpp) -> float2 {
        return make_float2(vo.x + fc + QG_COEF * vpp.x, vo.y + fc + QG_COEF * vpp.y);
    };
    auto consume = [&](int k, float2 qm, float2 qa, float2 qb, float2 qp) {
        const float qax = qa.x * m0,  qay = qa.y * m1;
        const float qbx = qb.x * mb0, qby = qb.y * mb1;
        vals[k] += (qax + qay) + (qbx + qby);
        ssqt += qax * qax + qay * qay + qbx * qbx + qby * qby;
        const float2 gla = sm2(qb, qm, sr_a);        // row clamps folded via vo selects
        const float2 glb = sm2(qp, qa, sr_mb);
        const float qaL = __shfl_up(qa.y, 1), qaR = __shfl_down(qa.x, 1);
        const float qbL = __shfl_up(qb.y, 1), qbR = __shfl_down(qb.x, 1);
        const float gnax = (qa.y - (e0 ? qa.x : qaL)) * sa0;
        const float gnay = ((e1 ? qa.y : qaR) - qa.x) * sa1;
        const float gnbx = (qb.y - (e0 ? qb.x : qbL)) * sb0;
        const float gnby = ((e1 ? qb.y : qbR) - qb.x) * sb1;
        grad += m0  * (gla.x * gla.x + gnax * gnax) + m1  * (gla.y * gla.y + gnay * gnay)
              + mb0 * (glb.x * glb.x + gnbx * gnbx) + mb1 * (glb.y * glb.y + gnby * gnby);
    };

    // rolling state ONLY (R8/R11 lesson: NO level-indexed arrays)
    float2 vo2_m, vo1_m, pa_m, pb_m;
    float2 vo2_a, vo1_a, pa_a, pb_a;
    float2 vo2_b, vo1_b, pa_b, pb_b;
    float2 vo2_p, vo1_p, pa_p, pb_p;

    // named double-buffer registers (a / b) — statically swapped via even/odd unroll
    float2 u0a, u1a, u2a, u3a, u4a, u5a, vma, vaa, vba, vpa;
    float2 u0b, u1b, u2b, u3b, u4b, u5b, vmb, vab, vbb, vpb;

    const float* pu = u + (size_t)b * BATSTRIDE;
    const float* pv = v + (size_t)b * BATSTRIDE;

    #define LOADSET(S) do {                                                     \
        u0##S = ld2(pu + o_u0); u1##S = ld2(pu + o_u1); u2##S = ld2(pu + o_u2); \
        u3##S = ld2(pu + o_u3); u4##S = ld2(pu + o_u4); u5##S = ld2(pu + o_u5); \
        vm##S = ld2(pv + o_vm); va##S = ld2(pv + o_va);                         \
        vb##S = ld2(pv + o_vb); vp##S = ld2(pv + o_vp);                         \
        pu += SLICE; pv += SLICE;                                               \
    } while (0)

    // COMPUTE(L, S): R10's level body verbatim on buffer S (math order identical)
    #define COMPUTE(L, S) do {                                                            \
        const float wl = wlev[(L)];                                                       \
        wu_a.x = fmaf(wl, u2##S.x, wu_a.x);  wu_a.y = fmaf(wl, u2##S.y, wu_a.y);          \
        wu_b.x = fmaf(wl, u3##S.x, wu_b.x);  wu_b.y = fmaf(wl, u3##S.y, wu_b.y);          \
        wvm.x = fmaf(wl, vm##S.x, wvm.x);    wvm.y = fmaf(wl, vm##S.y, wvm.y);            \
        wva.x = fmaf(wl, va##S.x, wva.x);    wva.y = fmaf(wl, va##S.y, wva.y);            \
        wvb.x = fmaf(wl, vb##S.x, wvb.x);    wvb.y = fmaf(wl, vb##S.y, wvb.y);            \
        wvp.x = fmaf(wl, vp##S.x, wvp.x);    wvp.y = fmaf(wl, vp##S.y, wvp.y);            \
        const float vmL_ = __shfl_up(vm##S.y, 1),  vmR_ = __shfl_down(vm##S.x, 1);        \
        const float vaL_ = __shfl_up(va##S.y, 1),  vaR_ = __shfl_down(va##S.x, 1);        \
        const float vbL_ = __shfl_up(vb##S.y, 1),  vbR_ = __shfl_down(vb##S.x, 1);        \
        const float vpL_ = __shfl_up(vp##S.y, 1),  vpR_ = __shfl_down(vp##S.x, 1);        \
        float2 com, coa, cob, cop;                                                        \
        com.x = (vm##S.y - (e0 ? vm##S.x : vmL_)) * sm0 - (u2##S.x - u0##S.x) * sr_mb;    \
        com.y = ((e1 ? vm##S.y : vmR_) - vm##S.x) * sm1 - (u2##S.y - u0##S.y) * sr_mb;    \
        coa.x = (va##S.y - (e0 ? va##S.x : vaL_)) * sa0 - (u3##S.x - u1##S.x) * sr_a;     \
        coa.y = ((e1 ? va##S.y : vaR_) - va##S.x) * sa1 - (u3##S.y - u1##S.y) * sr_a;     \
        cob.x = (vb##S.y - (e0 ? vb##S.x : vbL_)) * sb0 - (u4##S.x - u2##S.x) * sr_mb;    \
        cob.y = ((e1 ? vb##S.y : vbR_) - vb##S.x) * sb1 - (u4##S.y - u2##S.y) * sr_mb;    \
        cop.x = (vp##S.y - (e0 ? vp##S.x : vpL_)) * sp0 - (u5##S.x - u3##S.x) * sr_p;     \
        cop.y = ((e1 ? vp##S.y : vpR_) - vp##S.x) * sp1 - (u5##S.y - u3##S.y) * sr_p;     \
        if (rTop)  com = coa;                        /* clamped halo row == own row */    \
        if (rBotA) { cob = coa; cop = coa; }                                              \
        if ((L) == 0) {                                                                   \
            vo1_m = com; vo1_a = coa; vo1_b = cob; vo1_p = cop;                           \
        } else if ((L) == 1) {                                                            \
            pb_m = sm2(com, vo1_m, idp);  pb_a = sm2(coa, vo1_a, idp);                    \
            pb_b = sm2(cob, vo1_b, idp);  pb_p = sm2(cop, vo1_p, idp);                    \
            vo2_m = vo1_m; vo1_m = com;   vo2_a = vo1_a; vo1_a = coa;                     \
            vo2_b = vo1_b; vo1_b = cob;   vo2_p = vo1_p; vo1_p = cop;                     \
        } else {                                                                          \
            const float2 pn_m = sm2(com, vo2_m, i2dp);   /* vp1[l-1] */                   \
            const float2 pn_a = sm2(coa, vo2_a, i2dp);                                    \
            const float2 pn_b = sm2(cob, vo2_b, i2dp);                                    \
            const float2 pn_p = sm2(cop, vo2_p, i2dp);                                    \
            float2 qm, qa, qb, qp;                                                        \
            if ((L) == 2) {                                                               \
                qm = qgf(vo2_m, fc_m, sm2(pn_m, pb_m, idp));                              \
                qa = qgf(vo2_a, fc_a, sm2(pn_a, pb_a, idp));                              \
                qb = qgf(vo2_b, fc_b, sm2(pn_b, pb_b, idp));                              \
                qp = qgf(vo2_p, fc_p, sm2(pn_p, pb_p, idp));                              \
            } else {                                                                      \
                qm = qgf(vo2_m, fc_m, sm2(pn_m, pa_m, i2dp));                             \
                qa = qgf(vo2_a, fc_a, sm2(pn_a, pa_a, i2dp));                             \
                qb = qgf(vo2_b, fc_b, sm2(pn_b, pa_b, i2dp));                             \
                qp = qgf(vo2_p, fc_p, sm2(pn_p, pa_p, i2dp));                             \
            }                                                                             \
            consume((L) - 2, qm, qa, qb, qp);                                             \
            pa_m = pb_m; pb_m = pn_m;  vo2_m = vo1_m; vo1_m = com;                        \
            pa_a = pb_a; pb_a = pn_a;  vo2_a = vo1_a; vo1_a = coa;                        \
            pa_b = pb_b; pb_b = pn_b;  vo2_b = vo1_b; vo1_b = cob;                        \
            pa_p = pb_p; pb_p = pn_p;  vo2_p = vo1_p; vo1_p = cop;                        \
        }                                                                                 \
    } while (0)

    // ---- level loop: prefetch(l+1) issued BEFORE compute(l); 10 loads always in flight ----
    LOADSET(a);                                   // level 0
    #pragma unroll
    for (int l = 0; l < NLEV; ++l) {
        if ((l & 1) == 0) {
            if (l + 1 < NLEV) LOADSET(b);
            COMPUTE(l, a);
        } else {
            if (l + 1 < NLEV) LOADSET(a);
            COMPUTE(l, b);
        }
        __builtin_amdgcn_sched_barrier(0);        // bound hoisting to 1 level (R11 lesson)
    }
    #undef LOADSET
    #undef COMPUTE

    // tail: vp1[12] one-sided; emit qg[11], qg[12]
    {
        const float2 p12m = sm2(vo1_m, vo2_m, idp);
        const float2 p12a = sm2(vo1_a, vo2_a, idp);
        const float2 p12b = sm2(vo1_b, vo2_b, idp);
        const float2 p12p = sm2(vo1_p, vo2_p, idp);
        consume(11, qgf(vo2_m, fc_m, sm2(p12m, pa_m, i2dp)),
                    qgf(vo2_a, fc_a, sm2(p12a, pa_a, i2dp)),
                    qgf(vo2_b, fc_b, sm2(p12b, pa_b, i2dp)),
                    qgf(vo2_p, fc_p, sm2(p12p, pa_p, i2dp)));
        consume(12, qgf(vo1_m, fc_m, sm2(p12m, pb_m, idp)),
                    qgf(vo1_a, fc_a, sm2(p12a, pb_a, idp)),
                    qgf(vo1_b, fc_b, sm2(p12b, pb_b, idp)),
                    qgf(vo1_p, fc_p, sm2(p12p, pb_p, idp)));
    }

    vals[13] += ssqt;
    vals[14] += grad;
    // mass: du/dx in-lane/shfl + edge selects; dv/dy in-thread (clamped loads -> exact edges)
    {
        const float waL = __shfl_up(wu_a.y, 1), waR = __shfl_down(wu_a.x, 1);
        const float wbL = __shfl_up(wu_b.y, 1), wbR = __shfl_down(wu_b.x, 1);
        const float cdax = (wu_a.y - (e0 ? wu_a.x : waL)) * sa0 + (wvb.x - wvm.x) * sr_a;
        const float cday = ((e1 ? wu_a.y : waR) - wu_a.x) * sa1 + (wvb.y - wvm.y) * sr_a;
        const float cdbx = (wu_b.y - (e0 ? wu_b.x : wbL)) * sb0 + (wvp.x - wva.x) * sr_mb;
        const float cdby = ((e1 ? wu_b.y : wbR) - wu_b.x) * sb1 + (wvp.y - wva.y) * sr_mb;
        vals[15] += m0 * cdax * cdax + m1 * cday * cday
                  + mb0 * cdbx * cdbx + mb1 * cdby * cdby;
    }

    // ---- reduction: 4-step 16-lane-group butterfly + LDS transpose (16 values) ----
    #pragma unroll
    for (int k = 0; k < 16; ++k) {
        float x = vals[k];
        x += __shfl_xor(x, 8, 64);
        x += __shfl_xor(x, 4, 64);
        x += __shfl_xor(x, 2, 64);
        x += __shfl_xor(x, 1, 64);
        vals[k] = x;
    }
    const int g = tid >> 4, k16 = tid & 15;
    float myv = vals[0];
    #pragma unroll
    for (int k = 1; k < 16; ++k) if (k16 == k) myv = vals[k];   // static-index select
    red[g][k16] = myv;
    __syncthreads();

    if (tid < 16) {
        const int k = tid;
        float s = 0.f;
        #pragma unroll
        for (int g2 = 0; g2 < 16; ++g2) s += red[g2][k];
        int target;
        if (k < 13)       target = ACC_SUM + b * 13 + k;
        else if (k == 13) target = ACC_SSQ + b;
        else if (k == 14) target = ACC_GRAD;
        else              target = ACC_MASS;
        const int bank = (b * NWGX + blockIdx.x) & (NBANK - 1);
        atomicAdd(&ws[WS_ACC + bank * BANKSTRIDE + target], s);
    }
}

// ---------------- finalize: sum banks, apply formulas ----------------
__global__ void pl_finalize_kernel(const float* __restrict__ ws, float* __restrict__ out) {
    __shared__ float tot[N_ACC];
    const int t = threadIdx.x;
    if (t < N_ACC) {
        float s = 0.f;
        for (int bk = 0; bk < NBANK; ++bk) s += ws[WS_ACC + bk * BANKSTRIDE + t];
        tot[t] = s;
    }
    __syncthreads();
    if (t == 0) {
        const float N = (float)SLICE;
        float s2 = 0.f;
        for (int s = 0; s < 2 * NLEV; ++s) s2 += tot[ACC_SUM + s] * tot[ACC_SUM + s];
        const float ssq = tot[ACC_SSQ + 0] + tot[ACC_SSQ + 1];
        float vmean = (ssq - s2 / N) / (N - 1.0f) * (1.0f / (2.0f * NLEV));
        float gmean = tot[ACC_GRAD] / (float)(NBATCH * NLEV * SLICE);
        float mmean = tot[ACC_MASS] / (float)(NBATCH * SLICE);
        out[0] = vmean + 0.1f * gmean + mmean;          // spectra_loss statically 0
    }
}

extern "C" void kernel_launch(void* const* d_in, const int* in_sizes, int n_in,
                              void* d_out, int out_size, void* d_ws, size_t ws_size,
                              hipStream_t stream) {
    const float* u    = (const float*)d_in[0];
    const float* v    = (const float*)d_in[1];
    const float* plev = (const float*)d_in[2];
    float* ws  = (float*)d_ws;
    float* out = (float*)d_out;

    hipLaunchKernelGGL(pl_setup_kernel, dim3(1), dim3(1024), 0, stream, plev, ws);
    hipLaunchKernelGGL(pl_rc22p_kernel, dim3(NWGX, NBATCH), dim3(256), 0, stream, u, v, ws);
    hipLaunchKernelGGL(pl_finalize_kernel, dim3(1), dim3(64), 0, stream, ws, out);
}